// Round 9
// baseline (49.932 us; speedup 1.0000x reference)
//
#include <hip/hip_runtime.h>
#include <cmath>

#define B_ 4
#define L_ 8192
#define N_ 16
#define H_ 64

typedef float f32x4 __attribute__((ext_vector_type(4)));

// ---------------------------------------------------------------------------
// Kernel A: per-row segment-reset positions. 32 blocks = 4 rows x 8 chunks;
// each block redundantly scans its row's 8192 lengths (cheap, 64 KB) and
// fills its own 1024-element chunk of j (one branchless searchsorted per
// thread).
// ---------------------------------------------------------------------------
__global__ __launch_bounds__(1024)
void pos_kernel(const long long* __restrict__ idx, float* __restrict__ pos) {
    __shared__ int csum[L_];
    __shared__ int wp[17];
    const int b     = blockIdx.x >> 3;      // batch row
    const int chunk = blockIdx.x & 7;       // which 1024-slice of j
    const int tid   = threadIdx.x;          // 1024 threads
    constexpr int CHUNK = L_ / 1024;        // 8 lengths per thread

    const long long* row = idx + (size_t)b * L_;

    int local[CHUNK];
    int s = 0;
#pragma unroll
    for (int i = 0; i < CHUNK; ++i) {
        s += (int)row[tid * CHUNK + i];
        local[i] = s;
    }

    const int lane = tid & 63, wv = tid >> 6;   // 16 waves
    int scan = s;
#pragma unroll
    for (int off = 1; off < 64; off <<= 1) {
        int n = __shfl_up(scan, off);
        if (lane >= off) scan += n;
    }
    if (lane == 63) wp[wv + 1] = scan;
    if (tid == 0)   wp[0] = 0;
    __syncthreads();
    if (tid == 0) {
        int a = 0;
        for (int i = 1; i <= 16; ++i) { a += wp[i]; wp[i] = a; }
    }
    __syncthreads();

    const int off0 = wp[wv] + (scan - s);
#pragma unroll
    for (int i = 0; i < CHUNK; ++i) csum[tid * CHUNK + i] = off0 + local[i];
    __syncthreads();

    const int total = csum[L_ - 1];

    // this block's single query: j = chunk*1024 + tid
    const int j = chunk * 1024 + tid;
    int p = 0;
#pragma unroll
    for (int k = L_ / 2; k > 0; k >>= 1)
        p += (csum[p + k - 1] <= j) ? k : 0;
    const int excl = p ? csum[p - 1] : 0;
    pos[(size_t)b * L_ + j] = (j < total) ? (float)(j - excl) : 0.f;
}

// ---------------------------------------------------------------------------
// Kernel B: contiguous streaming RoPE, one WAVE per TWO (b,l) rows.
// Lane float4 index: v = (wave*2)*256 + lane + i*64, i = 0..7 — contiguous
// across the row boundary (i=0..3 row0, i=4..7 row1), so all 8 cached loads
// issue upfront (128 B in flight per thread) and every wave load/store
// instruction covers 1024 contiguous bytes. Trig computed once per row per
// thread (qp = lane&15 iteration-invariant). Rotate-half partner = lane^8
// via __shfl_xor; sign folded into sin:
//   out = x*cos + (qp<8 ? -1 : +1)*partner*sin
// Grid: B*L/2 = 16384 waves -> 4096 blocks x 256 threads.
// ---------------------------------------------------------------------------
__global__ __launch_bounds__(256)
void rope_kernel(const float* __restrict__ x,
                 const float* __restrict__ pos,
                 float* __restrict__ out) {
    const int    t    = blockIdx.x * 256 + threadIdx.x;
    const int    lane = threadIdx.x & 63;
    const int    qp   = lane & 15;            // float4 index within head row
    const size_t bl0  = ((size_t)t >> 6) * 2; // first of this wave's two rows
    const size_t base = bl0 * 256 + (size_t)lane;   // float4 index, i=0

    const float p0 = pos[bl0];
    const float p1 = pos[bl0 + 1];

    constexpr float NEG_LN_BASE_OVER_32 = -0.28782313662425f; // -ln(10000)/32
    constexpr float INV_2PI             = 0.15915493667126f;  // 1/(2*pi)
    const float sgn = (qp < 8) ? -1.f : 1.f;

    float f[4];
#pragma unroll
    for (int j = 0; j < 4; ++j)
        f[j] = __expf((float)((qp & 7) * 4 + j) * NEG_LN_BASE_OVER_32) * INV_2PI;

    float cv[2][4], ssv[2][4];
#pragma unroll
    for (int r = 0; r < 2; ++r) {
        const float p = r ? p1 : p0;
#pragma unroll
        for (int j = 0; j < 4; ++j) {
            float ph = p * f[j];
            ph -= floorf(ph);                    // revolutions -> [0,1)
            cv[r][j]  = __builtin_amdgcn_cosf(ph);
            ssv[r][j] = sgn * __builtin_amdgcn_sinf(ph);
        }
    }

    // issue all 8 cached loads upfront (128 B in flight per thread)
    f32x4 a[8];
#pragma unroll
    for (int i = 0; i < 8; ++i)
        a[i] = *((const f32x4*)(x) + base + (size_t)(i * 64));

#pragma unroll
    for (int i = 0; i < 8; ++i) {
        const int r = i >> 2;                    // which row's trig
        f32x4 pr;
#pragma unroll
        for (int j = 0; j < 4; ++j) pr[j] = __shfl_xor(a[i][j], 8);
        f32x4 o;
#pragma unroll
        for (int j = 0; j < 4; ++j) o[j] = a[i][j] * cv[r][j] + pr[j] * ssv[r][j];
        *((f32x4*)(out) + base + (size_t)(i * 64)) = o;
    }
}

extern "C" void kernel_launch(void* const* d_in, const int* in_sizes, int n_in,
                              void* d_out, int out_size, void* d_ws, size_t ws_size,
                              hipStream_t stream) {
    const float*     x   = (const float*)d_in[0];
    const long long* idx = (const long long*)d_in[1];
    float*           out = (float*)d_out;
    float*           pos = (float*)d_ws;   // B_*L_ floats = 128 KiB scratch

    pos_kernel<<<32, 1024, 0, stream>>>(idx, pos);

    // B*L/2 waves = 16384 -> 4096 blocks of 256 threads (4 waves each)
    rope_kernel<<<4096, 256, 0, stream>>>(x, pos, out);
}

// Round 10
// 49.035 us; speedup vs baseline: 1.0183x; 1.0183x over previous
//
#include <hip/hip_runtime.h>
#include <cmath>

#define B_ 4
#define L_ 8192
#define N_ 16
#define H_ 64

typedef float f32x4 __attribute__((ext_vector_type(4)));

// ---------------------------------------------------------------------------
// Kernel A: per-row segment-reset positions. 32 blocks = 4 rows x 8 chunks;
// each block redundantly scans its row's 8192 lengths (cheap, 64 KB) and
// fills its own 1024-element chunk of j (one branchless searchsorted per
// thread).
// ---------------------------------------------------------------------------
__global__ __launch_bounds__(1024)
void pos_kernel(const long long* __restrict__ idx, float* __restrict__ pos) {
    __shared__ int csum[L_];
    __shared__ int wp[17];
    const int b     = blockIdx.x >> 3;      // batch row
    const int chunk = blockIdx.x & 7;       // which 1024-slice of j
    const int tid   = threadIdx.x;          // 1024 threads
    constexpr int CHUNK = L_ / 1024;        // 8 lengths per thread

    const long long* row = idx + (size_t)b * L_;

    int local[CHUNK];
    int s = 0;
#pragma unroll
    for (int i = 0; i < CHUNK; ++i) {
        s += (int)row[tid * CHUNK + i];
        local[i] = s;
    }

    const int lane = tid & 63, wv = tid >> 6;   // 16 waves
    int scan = s;
#pragma unroll
    for (int off = 1; off < 64; off <<= 1) {
        int n = __shfl_up(scan, off);
        if (lane >= off) scan += n;
    }
    if (lane == 63) wp[wv + 1] = scan;
    if (tid == 0)   wp[0] = 0;
    __syncthreads();
    if (tid == 0) {
        int a = 0;
        for (int i = 1; i <= 16; ++i) { a += wp[i]; wp[i] = a; }
    }
    __syncthreads();

    const int off0 = wp[wv] + (scan - s);
#pragma unroll
    for (int i = 0; i < CHUNK; ++i) csum[tid * CHUNK + i] = off0 + local[i];
    __syncthreads();

    const int total = csum[L_ - 1];

    // this block's single query: j = chunk*1024 + tid
    const int j = chunk * 1024 + tid;
    int p = 0;
#pragma unroll
    for (int k = L_ / 2; k > 0; k >>= 1)
        p += (csum[p + k - 1] <= j) ? k : 0;
    const int excl = p ? csum[p - 1] : 0;
    pos[(size_t)b * L_ + j] = (j < total) ? (float)(j - excl) : 0.f;
}

// ---------------------------------------------------------------------------
// Kernel B: contiguous streaming RoPE with per-thread trig reuse.
// One WAVE owns one (b,l) row: 64 lanes x 4 float4 iters = 256 float4s.
// Every wave load/store instruction covers 1024 contiguous bytes.
// CACHED loads + CACHED stores (A/B-tested best: NT only helped when the
// access pattern was fragmented; on the contiguous pattern the plain-copy
// config wins). qp = lane&15, bl = t>>6 iteration-invariant -> 4 sin/cos
// pairs computed once per thread. Rotate-half partner = lane^8 via
// __shfl_xor; sign folded into sin:
//   out = x*cos + (qp<8 ? -1 : +1)*partner*sin
// Measured: rope ~46 us = 93% of the 6.29 TB/s float4-copy ceiling.
// ---------------------------------------------------------------------------
__global__ __launch_bounds__(256)
void rope_kernel(const float* __restrict__ x,
                 const float* __restrict__ pos,
                 float* __restrict__ out) {
    const int    t    = blockIdx.x * 256 + threadIdx.x;
    const int    lane = threadIdx.x & 63;
    const int    qp   = lane & 15;          // float4 index within head row
    const size_t bl   = (size_t)t >> 6;     // b*L + l (wave-uniform)
    const size_t base = bl * 256 + (size_t)lane;   // float4 index, iter 0

    const float p = pos[bl];

    constexpr float NEG_LN_BASE_OVER_32 = -0.28782313662425f; // -ln(10000)/32
    constexpr float INV_2PI             = 0.15915493667126f;  // 1/(2*pi)
    const float sgn = (qp < 8) ? -1.f : 1.f;

    float cv[4], ssv[4];
#pragma unroll
    for (int j = 0; j < 4; ++j) {
        const float f = __expf((float)((qp & 7) * 4 + j) * NEG_LN_BASE_OVER_32)
                        * INV_2PI;
        float ph = p * f;
        ph -= floorf(ph);                        // revolutions -> [0,1)
        cv[j]  = __builtin_amdgcn_cosf(ph);      // v_cos_f32
        ssv[j] = sgn * __builtin_amdgcn_sinf(ph);
    }

    // issue all 4 loads first (4 in-flight per thread)
    f32x4 a[4];
#pragma unroll
    for (int i = 0; i < 4; ++i)
        a[i] = *((const f32x4*)(x) + base + (size_t)(i * 64));   // cached load

#pragma unroll
    for (int i = 0; i < 4; ++i) {
        f32x4 pr;
#pragma unroll
        for (int j = 0; j < 4; ++j) pr[j] = __shfl_xor(a[i][j], 8);
        f32x4 o;
#pragma unroll
        for (int j = 0; j < 4; ++j) o[j] = a[i][j] * cv[j] + pr[j] * ssv[j];
        *((f32x4*)(out) + base + (size_t)(i * 64)) = o;          // cached store
    }
}

extern "C" void kernel_launch(void* const* d_in, const int* in_sizes, int n_in,
                              void* d_out, int out_size, void* d_ws, size_t ws_size,
                              hipStream_t stream) {
    const float*     x   = (const float*)d_in[0];
    const long long* idx = (const long long*)d_in[1];
    float*           out = (float*)d_out;
    float*           pos = (float*)d_ws;   // B_*L_ floats = 128 KiB scratch

    pos_kernel<<<32, 1024, 0, stream>>>(idx, pos);

    // B*L waves = 32768 -> 8192 blocks of 256 threads (4 waves each)
    rope_kernel<<<8192, 256, 0, stream>>>(x, pos, out);
}